// Round 4
// baseline (674.753 us; speedup 1.0000x reference)
//
#include <hip/hip_runtime.h>

// Problem constants (from reference)
#define KSZ   7
#define KK    49          // K*K
#define GCH   16          // group_channels
#define CIN   256
#define MID   64
#define NGRP  16
#define WID   56
#define HWSZ  3136        // 56*56
#define NB    4
#define NPIX  (NB * HWSZ) // 12544
#define EPSV  1e-5f

// ws layout (floats):
// [0..63]    per-channel sum
// [64..127]  per-channel sumsq
// [128..191] a  (gamma * rsqrt(var+eps))
// [192..255] c  (beta - mu*a)
// [256 ...]  t_pre  [pix][MID]  (transposed: 64 contiguous per pixel)

__global__ __launch_bounds__(256, 8) void k1_conv1(const float* __restrict__ x,
                                                   const float* __restrict__ w1,
                                                   const float* __restrict__ b1,
                                                   float* __restrict__ ws) {
    const int tid = threadIdx.x;
    const int pix = blockIdx.x * 256 + tid;       // 49 blocks * 256 = 12544
    const int ob  = blockIdx.y * 4;               // 16 chunks of 4 mid-channels
    const int b   = pix / HWSZ;
    const int hw  = pix - b * HWSZ;

    float acc[4];
#pragma unroll
    for (int i = 0; i < 4; ++i) acc[i] = b1[ob + i];

    const float* xp = x + (size_t)b * CIN * HWSZ + hw;
#pragma unroll 8
    for (int c = 0; c < CIN; ++c) {
        const float xv = xp[(size_t)c * HWSZ];
#pragma unroll
        for (int i = 0; i < 4; ++i)
            acc[i] = fmaf(w1[(ob + i) * CIN + c], xv, acc[i]);   // uniform -> s_load
    }

    // transposed store: t[pix][64]
    float4* tp = (float4*)(ws + 256 + (size_t)pix * MID + ob);
    *tp = make_float4(acc[0], acc[1], acc[2], acc[3]);

    // --- batch stats: wave shuffle reduce, then LDS, then global atomics ---
    __shared__ float bs[4];
    __shared__ float bq[4];
    if (tid < 4) { bs[tid] = 0.f; bq[tid] = 0.f; }
    __syncthreads();

#pragma unroll
    for (int i = 0; i < 4; ++i) {
        float s = acc[i];
        float q = acc[i] * acc[i];
#pragma unroll
        for (int m = 1; m < 64; m <<= 1) {
            s += __shfl_xor(s, m, 64);
            q += __shfl_xor(q, m, 64);
        }
        if ((tid & 63) == 0) {
            atomicAdd(&bs[i], s);
            atomicAdd(&bq[i], q);
        }
    }
    __syncthreads();
    if (tid < 4) {
        atomicAdd(&ws[ob + tid],      bs[tid]);
        atomicAdd(&ws[64 + ob + tid], bq[tid]);
    }
}

__global__ void k2_stats(float* __restrict__ ws,
                         const float* __restrict__ gamma,
                         const float* __restrict__ beta) {
    const int o = threadIdx.x;  // 64 threads
    const float n   = (float)NPIX;
    const float mu  = ws[o] / n;
    const float var = ws[64 + o] / n - mu * mu;
    const float a   = gamma[o] * rsqrtf(var + EPSV);
    ws[128 + o] = a;
    ws[192 + o] = beta[o] - mu * a;
}

// amdgpu_waves_per_eu(4,4): pin occupancy to exactly 4 waves/EU -> 128-VGPR
// budget. __launch_bounds__'s 2nd arg is only a MINIMUM; without the max the
// allocator targets 8 waves/EU (64 VGPR) and spills wgt[49] to scratch
// (R3: WRITE_SIZE 86 MB vs 12.5 MB of actual output).
__global__ __launch_bounds__(64)
__attribute__((amdgpu_waves_per_eu(4, 4)))
void k3_fused(const float* __restrict__ x,
              const float* __restrict__ w2,
              const float* __restrict__ b2,
              const float* __restrict__ ws,
              float* __restrict__ out) {
    const int tid = threadIdx.x;
    const int pix = blockIdx.x * 64 + tid;        // 196 blocks * 64
    const int g   = blockIdx.y;                   // group, wave-uniform
    const int b   = pix / HWSZ;
    const int hw  = pix - b * HWSZ;
    const int h   = hw / WID;
    const int w   = hw - h * WID;

    // ---------- Phase A: per-pixel kernel weights wgt[49] ----------
    float wgt[KK];
    const float* w2g = w2 + (size_t)g * KK * MID;
    const float* b2g = b2 + (size_t)g * KK;
#pragma unroll
    for (int k = 0; k < KK; ++k) wgt[k] = b2g[k];

    const float* tb = ws + 256 + (size_t)pix * MID;
    for (int oc = 0; oc < MID; oc += 8) {
        const float4 v0 = *(const float4*)(tb + oc);
        const float4 v1 = *(const float4*)(tb + oc + 4);
        float tv[8];
        tv[0] = fmaxf(0.f, fmaf(ws[128 + oc + 0], v0.x, ws[192 + oc + 0]));
        tv[1] = fmaxf(0.f, fmaf(ws[128 + oc + 1], v0.y, ws[192 + oc + 1]));
        tv[2] = fmaxf(0.f, fmaf(ws[128 + oc + 2], v0.z, ws[192 + oc + 2]));
        tv[3] = fmaxf(0.f, fmaf(ws[128 + oc + 3], v0.w, ws[192 + oc + 3]));
        tv[4] = fmaxf(0.f, fmaf(ws[128 + oc + 4], v1.x, ws[192 + oc + 4]));
        tv[5] = fmaxf(0.f, fmaf(ws[128 + oc + 5], v1.y, ws[192 + oc + 5]));
        tv[6] = fmaxf(0.f, fmaf(ws[128 + oc + 6], v1.z, ws[192 + oc + 6]));
        tv[7] = fmaxf(0.f, fmaf(ws[128 + oc + 7], v1.w, ws[192 + oc + 7]));
#pragma unroll
        for (int k = 0; k < KK; ++k) {
#pragma unroll
            for (int o = 0; o < 8; ++o)
                wgt[k] = fmaf(w2g[k * MID + oc + o], tv[o], wgt[k]);  // uniform
        }
    }

    // ---------- Phase B: involution (weighted 7x7 gather) ----------
    float acc[GCH];
#pragma unroll
    for (int cc = 0; cc < GCH; ++cc) acc[cc] = 0.f;

    const float* xg = x + ((size_t)b * CIN + (size_t)g * GCH) * HWSZ;

#pragma unroll
    for (int k = 0; k < KK; ++k) {
        const int di = k / 7 - 3;
        const int dj = k % 7 - 3;
        const int hh  = h + di;
        const int wwv = w + dj;
        const bool valid = ((unsigned)hh < 56u) && ((unsigned)wwv < 56u);
        const float wm = valid ? wgt[k] : 0.f;
        const float* xb = xg + (valid ? hh * WID + wwv : 0);
#pragma unroll
        for (int cc = 0; cc < GCH; ++cc)
            acc[cc] = fmaf(wm, xb[(size_t)cc * HWSZ], acc[cc]);
    }

    float* ob = out + ((size_t)b * CIN + (size_t)g * GCH) * HWSZ + hw;
#pragma unroll
    for (int cc = 0; cc < GCH; ++cc) ob[(size_t)cc * HWSZ] = acc[cc];
}

extern "C" void kernel_launch(void* const* d_in, const int* in_sizes, int n_in,
                              void* d_out, int out_size, void* d_ws, size_t ws_size,
                              hipStream_t stream) {
    const float* x     = (const float*)d_in[0];
    const float* w1    = (const float*)d_in[1];
    const float* b1    = (const float*)d_in[2];
    const float* gamma = (const float*)d_in[3];
    const float* beta  = (const float*)d_in[4];
    const float* w2    = (const float*)d_in[5];
    const float* b2    = (const float*)d_in[6];
    float* out = (float*)d_out;
    float* ws  = (float*)d_ws;

    // zero the stats accumulators (first 128 floats)
    hipMemsetAsync(ws, 0, 128 * sizeof(float), stream);

    k1_conv1<<<dim3(49, 16), 256, 0, stream>>>(x, w1, b1, ws);
    k2_stats<<<1, 64, 0, stream>>>(ws, gamma, beta);
    k3_fused<<<dim3(196, 16), 64, 0, stream>>>(x, w2, b2, ws, out);
}

// Round 5
// 148.135 us; speedup vs baseline: 4.5550x; 4.5550x over previous
//
#include <hip/hip_runtime.h>

// Problem constants (from reference)
#define KSZ   7
#define KK    49          // K*K
#define GCH   16          // group_channels
#define CIN   256
#define MID   64
#define NGRP  16
#define WID   56
#define HWSZ  3136        // 56*56
#define NB    4
#define NPIX  (NB * HWSZ) // 12544
#define EPSV  1e-5f

// ws layout (floats):
// [0..63]    per-channel sum
// [64..127]  per-channel sumsq
// [128..191] a  (gamma * rsqrt(var+eps))
// [192..255] c  (beta - mu*a)
// [256 ...]  t  [MID][NPIX]  (plane-major: t[o][pix], coalesced reads in k3)

__global__ __launch_bounds__(256) void k1_conv1(const float* __restrict__ x,
                                                const float* __restrict__ w1,
                                                const float* __restrict__ b1,
                                                float* __restrict__ ws) {
    const int tid = threadIdx.x;
    const int pix = blockIdx.x * 256 + tid;       // 49 blocks * 256 = 12544
    const int ob  = blockIdx.y * 16;              // 4 chunks of 16 mid-channels
    const int b   = pix / HWSZ;
    const int hw  = pix - b * HWSZ;

    float acc[16];
#pragma unroll
    for (int i = 0; i < 16; ++i) acc[i] = b1[ob + i];

    const float* xp = x + (size_t)b * CIN * HWSZ + hw;
#pragma unroll 4
    for (int c = 0; c < CIN; ++c) {
        const float xv = xp[(size_t)c * HWSZ];
#pragma unroll
        for (int i = 0; i < 16; ++i)
            acc[i] = fmaf(w1[(ob + i) * CIN + c], xv, acc[i]);   // uniform -> s_load
    }

    // plane-major store: t[o][pix]
    float* tp = ws + 256 + (size_t)ob * NPIX + pix;
#pragma unroll
    for (int i = 0; i < 16; ++i) tp[(size_t)i * NPIX] = acc[i];

    // --- batch stats: wave shuffle reduce -> LDS -> global atomics ---
    __shared__ float bs[16];
    __shared__ float bq[16];
    if (tid < 16) { bs[tid] = 0.f; bq[tid] = 0.f; }
    __syncthreads();

#pragma unroll
    for (int i = 0; i < 16; ++i) {
        float s = acc[i];
        float q = acc[i] * acc[i];
#pragma unroll
        for (int m = 1; m < 64; m <<= 1) {
            s += __shfl_xor(s, m, 64);
            q += __shfl_xor(q, m, 64);
        }
        if ((tid & 63) == 0) {
            atomicAdd(&bs[i], s);
            atomicAdd(&bq[i], q);
        }
    }
    __syncthreads();
    if (tid < 16) {
        atomicAdd(&ws[ob + tid],      bs[tid]);
        atomicAdd(&ws[64 + ob + tid], bq[tid]);
    }
}

__global__ void k2_stats(float* __restrict__ ws,
                         const float* __restrict__ gamma,
                         const float* __restrict__ beta) {
    const int o = threadIdx.x;  // 64 threads
    const float n   = (float)NPIX;
    const float mu  = ws[o] / n;
    const float var = ws[64 + o] / n - mu * mu;
    const float a   = gamma[o] * rsqrtf(var + EPSV);
    ws[128 + o] = a;
    ws[192 + o] = beta[o] - mu * a;
}

// Live-set-by-construction: t tile in LDS; 49 taps processed as 7 chunks of 7
// (aw[7] accumulators), applied to acc[16] immediately. ~40 live VGPRs -> no
// spill even at the allocator's default 64-VGPR / 8-waves-per-EU target.
__global__ __launch_bounds__(256) void k3_fused(const float* __restrict__ x,
                                                const float* __restrict__ w2,
                                                const float* __restrict__ b2,
                                                const float* __restrict__ ws,
                                                float* __restrict__ out) {
    __shared__ float tl[MID][256];                // 64 KB
    const int tid = threadIdx.x;
    const int pix = blockIdx.x * 256 + tid;       // 49 blocks * 256
    const int g   = blockIdx.y;                   // group, wave-uniform
    const int b   = pix / HWSZ;
    const int hw  = pix - b * HWSZ;
    const int h   = hw / WID;
    const int w   = hw - h * WID;

    // stage BN+ReLU(t) for this block's 256 pixels
    const float* tcol = ws + 256 + pix;
#pragma unroll 8
    for (int o = 0; o < MID; ++o) {
        const float v = tcol[(size_t)o * NPIX];   // coalesced
        tl[o][tid] = fmaxf(0.f, fmaf(ws[128 + o], v, ws[192 + o]));
    }
    __syncthreads();

    float acc[GCH];
#pragma unroll
    for (int cc = 0; cc < GCH; ++cc) acc[cc] = 0.f;

    const float* w2g = w2 + (size_t)g * KK * MID;
    const float* b2g = b2 + (size_t)g * KK;
    const int   xbase = (b * CIN + g * GCH) * HWSZ;   // < 2^24, fits int

    for (int kc = 0; kc < 7; ++kc) {              // tap row (di = kc-3, chunk-uniform)
        float aw[7];
#pragma unroll
        for (int j = 0; j < 7; ++j) aw[j] = b2g[kc * 7 + j];

#pragma unroll 8
        for (int o = 0; o < MID; ++o) {
            const float tv = tl[o][tid];          // 2-way bank alias: free
#pragma unroll
            for (int j = 0; j < 7; ++j)
                aw[j] = fmaf(w2g[(kc * 7 + j) * MID + o], tv, aw[j]);  // uniform
        }

        const int  hh    = h + kc - 3;
        const bool rowok = (unsigned)hh < 56u;
#pragma unroll
        for (int j = 0; j < 7; ++j) {
            const int  ww = w + j - 3;
            const bool ok = rowok && ((unsigned)ww < 56u);
            const float wm = ok ? aw[j] : 0.f;
            const int  off = ok ? (hh * WID + ww) : 0;
            const float* xb = x + xbase + off;
#pragma unroll
            for (int cc = 0; cc < GCH; ++cc)
                acc[cc] = fmaf(wm, xb[(size_t)cc * HWSZ], acc[cc]);
        }
    }

    float* ob = out + (size_t)xbase + hw;
#pragma unroll
    for (int cc = 0; cc < GCH; ++cc) ob[(size_t)cc * HWSZ] = acc[cc];
}

extern "C" void kernel_launch(void* const* d_in, const int* in_sizes, int n_in,
                              void* d_out, int out_size, void* d_ws, size_t ws_size,
                              hipStream_t stream) {
    const float* x     = (const float*)d_in[0];
    const float* w1    = (const float*)d_in[1];
    const float* b1    = (const float*)d_in[2];
    const float* gamma = (const float*)d_in[3];
    const float* beta  = (const float*)d_in[4];
    const float* w2    = (const float*)d_in[5];
    const float* b2    = (const float*)d_in[6];
    float* out = (float*)d_out;
    float* ws  = (float*)d_ws;

    // zero the stats accumulators (first 128 floats)
    hipMemsetAsync(ws, 0, 128 * sizeof(float), stream);

    k1_conv1<<<dim3(49, 4), 256, 0, stream>>>(x, w1, b1, ws);
    k2_stats<<<1, 64, 0, stream>>>(ws, gamma, beta);
    k3_fused<<<dim3(49, 16), 256, 0, stream>>>(x, w2, b2, ws, out);
}

// Round 6
// 103.959 us; speedup vs baseline: 6.4906x; 1.4249x over previous
//
#include <hip/hip_runtime.h>

// Problem constants (from reference)
#define KSZ   7
#define KK    49          // K*K
#define GCH   16          // group_channels
#define CIN   256
#define MID   64
#define NGRP  16
#define WID   56
#define HWSZ  3136        // 56*56
#define NB    4
#define NPIX  (NB * HWSZ) // 12544
#define EPSV  1e-5f

// ws layout (floats):
// [0..63]    per-channel sum
// [64..127]  per-channel sumsq
// [128..191] a  (gamma * rsqrt(var+eps))
// [192..255] c  (beta - mu*a)
// [256 ...]  t  [MID][NPIX]  (plane-major: t[o][pix], coalesced reads in k3)

__global__ __launch_bounds__(256) void k1_conv1(const float* __restrict__ x,
                                                const float* __restrict__ w1,
                                                const float* __restrict__ b1,
                                                float* __restrict__ ws) {
    const int tid = threadIdx.x;
    const int pix = blockIdx.x * 256 + tid;       // 49 blocks * 256 = 12544
    const int ob  = blockIdx.y * 4;               // 16 chunks of 4 mid-channels
    const int b   = pix / HWSZ;
    const int hw  = pix - b * HWSZ;

    float acc[4];
#pragma unroll
    for (int i = 0; i < 4; ++i) acc[i] = b1[ob + i];

    const float* xp = x + (size_t)b * CIN * HWSZ + hw;
#pragma unroll 16
    for (int c = 0; c < CIN; ++c) {
        const float xv = xp[(size_t)c * HWSZ];
#pragma unroll
        for (int i = 0; i < 4; ++i)
            acc[i] = fmaf(w1[(ob + i) * CIN + c], xv, acc[i]);   // uniform -> s_load
    }

    // plane-major store: t[o][pix]
    float* tp = ws + 256 + (size_t)ob * NPIX + pix;
#pragma unroll
    for (int i = 0; i < 4; ++i) tp[(size_t)i * NPIX] = acc[i];

    // --- batch stats: wave shuffle reduce -> LDS -> global atomics ---
    __shared__ float bs[4];
    __shared__ float bq[4];
    if (tid < 4) { bs[tid] = 0.f; bq[tid] = 0.f; }
    __syncthreads();

#pragma unroll
    for (int i = 0; i < 4; ++i) {
        float s = acc[i];
        float q = acc[i] * acc[i];
#pragma unroll
        for (int m = 1; m < 64; m <<= 1) {
            s += __shfl_xor(s, m, 64);
            q += __shfl_xor(q, m, 64);
        }
        if ((tid & 63) == 0) {
            atomicAdd(&bs[i], s);
            atomicAdd(&bq[i], q);
        }
    }
    __syncthreads();
    if (tid < 4) {
        atomicAdd(&ws[ob + tid],      bs[tid]);
        atomicAdd(&ws[64 + ob + tid], bq[tid]);
    }
}

__global__ void k2_stats(float* __restrict__ ws,
                         const float* __restrict__ gamma,
                         const float* __restrict__ beta) {
    const int o = threadIdx.x;  // 64 threads
    const float n   = (float)NPIX;
    const float mu  = ws[o] / n;
    const float var = ws[64 + o] / n - mu * mu;
    const float a   = gamma[o] * rsqrtf(var + EPSV);
    ws[128 + o] = a;
    ws[192 + o] = beta[o] - mu * a;
}

// Block = 128 pixels x 2 groups (256 threads). LDS tile 32 KB -> 5 blocks/CU
// (vs 64 KB -> 2 blocks/CU in R5, which gave 16.5% occupancy / 23% VALUBusy).
// Live set stays ~40 VGPR (acc[16]+aw[7]) -> no spill at the 88-VGPR budget.
__global__ __launch_bounds__(256) void k3_fused(const float* __restrict__ x,
                                                const float* __restrict__ w2,
                                                const float* __restrict__ b2,
                                                const float* __restrict__ ws,
                                                float* __restrict__ out) {
    __shared__ float tl[MID][128];                // 32 KB
    const int tid  = threadIdx.x;
    const int p    = tid & 127;                   // local pixel
    const int half = __builtin_amdgcn_readfirstlane(tid >> 7);  // wave-uniform
    const int pix  = blockIdx.x * 128 + p;        // 98 blocks * 128 = 12544
    const int g    = blockIdx.y * 2 + half;       // SGPR group index
    const int b    = pix / HWSZ;
    const int hw   = pix - b * HWSZ;
    const int h    = hw / WID;
    const int w    = hw - h * WID;

    // stage BN+ReLU(t): half 0 stages o=[0,32), half 1 stages o=[32,64)
    {
        const float* tcol = ws + 256 + blockIdx.x * 128 + p;
#pragma unroll 8
        for (int i = 0; i < 32; ++i) {
            const int o = half * 32 + i;          // SGPR
            const float v = tcol[(size_t)o * NPIX];   // coalesced
            tl[o][p] = fmaxf(0.f, fmaf(ws[128 + o], v, ws[192 + o]));
        }
    }
    __syncthreads();

    float acc[GCH];
#pragma unroll
    for (int cc = 0; cc < GCH; ++cc) acc[cc] = 0.f;

    const float* w2g = w2 + (size_t)g * KK * MID;
    const float* b2g = b2 + (size_t)g * KK;
    const int   xbase = (b * CIN + g * GCH) * HWSZ;

    for (int kc = 0; kc < 7; ++kc) {              // tap row (di = kc-3)
        float aw[7];
#pragma unroll
        for (int j = 0; j < 7; ++j) aw[j] = b2g[kc * 7 + j];

#pragma unroll 8
        for (int o = 0; o < MID; ++o) {
            const float tv = tl[o][p];            // conflict-free
#pragma unroll
            for (int j = 0; j < 7; ++j)
                aw[j] = fmaf(w2g[(kc * 7 + j) * MID + o], tv, aw[j]);  // s_load
        }

        const int  hh    = h + kc - 3;
        const bool rowok = (unsigned)hh < 56u;
#pragma unroll
        for (int j = 0; j < 7; ++j) {
            const int  ww = w + j - 3;
            const bool ok = rowok && ((unsigned)ww < 56u);
            const float wm = ok ? aw[j] : 0.f;
            const int  off = ok ? (hh * WID + ww) : 0;
            const float* xb = x + xbase + off;
#pragma unroll
            for (int cc = 0; cc < GCH; ++cc)
                acc[cc] = fmaf(wm, xb[(size_t)cc * HWSZ], acc[cc]);
        }
    }

    float* ob = out + (size_t)xbase + hw;
#pragma unroll
    for (int cc = 0; cc < GCH; ++cc) ob[(size_t)cc * HWSZ] = acc[cc];
}

extern "C" void kernel_launch(void* const* d_in, const int* in_sizes, int n_in,
                              void* d_out, int out_size, void* d_ws, size_t ws_size,
                              hipStream_t stream) {
    const float* x     = (const float*)d_in[0];
    const float* w1    = (const float*)d_in[1];
    const float* b1    = (const float*)d_in[2];
    const float* gamma = (const float*)d_in[3];
    const float* beta  = (const float*)d_in[4];
    const float* w2    = (const float*)d_in[5];
    const float* b2    = (const float*)d_in[6];
    float* out = (float*)d_out;
    float* ws  = (float*)d_ws;

    // zero the stats accumulators (first 128 floats)
    hipMemsetAsync(ws, 0, 128 * sizeof(float), stream);

    k1_conv1<<<dim3(49, 16), 256, 0, stream>>>(x, w1, b1, ws);
    k2_stats<<<1, 64, 0, stream>>>(ws, gamma, beta);
    k3_fused<<<dim3(98, 8), 256, 0, stream>>>(x, w2, b2, ws, out);
}

// Round 7
// 100.151 us; speedup vs baseline: 6.7374x; 1.0380x over previous
//
#include <hip/hip_runtime.h>

// Problem constants (from reference)
#define KSZ   7
#define KK    49          // K*K
#define GCH   16          // group_channels
#define CIN   256
#define MID   64
#define NGRP  16
#define WID   56
#define HWSZ  3136        // 56*56
#define NB    4
#define NPIX  (NB * HWSZ) // 12544
#define EPSV  1e-5f

// ws layout (floats):
// [0..63]    per-channel sum
// [64..127]  per-channel sumsq
// [128..191] a  (gamma * rsqrt(var+eps))
// [192..255] c  (beta - mu*a)
// [256 ...]  t  [MID][NPIX]  (plane-major: t[o][pix], coalesced reads in k3)

__global__ __launch_bounds__(256) void k1_conv1(const float* __restrict__ x,
                                                const float* __restrict__ w1,
                                                const float* __restrict__ b1,
                                                float* __restrict__ ws) {
    const int tid = threadIdx.x;
    const int pix = blockIdx.x * 256 + tid;       // 49 blocks * 256 = 12544
    const int ob  = blockIdx.y * 4;               // 16 chunks of 4 mid-channels
    const int b   = pix / HWSZ;
    const int hw  = pix - b * HWSZ;

    float acc[4];
#pragma unroll
    for (int i = 0; i < 4; ++i) acc[i] = b1[ob + i];

    const float* xp = x + (size_t)b * CIN * HWSZ + hw;
#pragma unroll 16
    for (int c = 0; c < CIN; ++c) {
        const float xv = xp[(size_t)c * HWSZ];
#pragma unroll
        for (int i = 0; i < 4; ++i)
            acc[i] = fmaf(w1[(ob + i) * CIN + c], xv, acc[i]);   // uniform -> s_load
    }

    // plane-major store: t[o][pix]
    float* tp = ws + 256 + (size_t)ob * NPIX + pix;
#pragma unroll
    for (int i = 0; i < 4; ++i) tp[(size_t)i * NPIX] = acc[i];

    // --- batch stats: wave shuffle reduce -> LDS -> global atomics ---
    __shared__ float bs[4];
    __shared__ float bq[4];
    if (tid < 4) { bs[tid] = 0.f; bq[tid] = 0.f; }
    __syncthreads();

#pragma unroll
    for (int i = 0; i < 4; ++i) {
        float s = acc[i];
        float q = acc[i] * acc[i];
#pragma unroll
        for (int m = 1; m < 64; m <<= 1) {
            s += __shfl_xor(s, m, 64);
            q += __shfl_xor(q, m, 64);
        }
        if ((tid & 63) == 0) {
            atomicAdd(&bs[i], s);
            atomicAdd(&bq[i], q);
        }
    }
    __syncthreads();
    if (tid < 4) {
        atomicAdd(&ws[ob + tid],      bs[tid]);
        atomicAdd(&ws[64 + ob + tid], bq[tid]);
    }
}

__global__ void k2_stats(float* __restrict__ ws,
                         const float* __restrict__ gamma,
                         const float* __restrict__ beta) {
    const int o = threadIdx.x;  // 64 threads
    const float n   = (float)NPIX;
    const float mu  = ws[o] / n;
    const float var = ws[64 + o] / n - mu * mu;
    const float a   = gamma[o] * rsqrtf(var + EPSV);
    ws[128 + o] = a;
    ws[192 + o] = beta[o] - mu * a;
}

// Phase A helper: slot computes taps [T0, T0+NT) for its pixel p.
// Live set aw[NT<=13] + tv[8] ~ 28 VGPR -> no spill at default budget.
template <int T0, int NT>
__device__ inline void phaseA(const float* __restrict__ w2g,
                              const float* __restrict__ b2g,
                              const float (*__restrict__ tl)[128],
                              float (*__restrict__ wgt)[128], int p) {
    float aw[NT];
#pragma unroll
    for (int t = 0; t < NT; ++t) aw[t] = b2g[T0 + t];
#pragma unroll
    for (int oc = 0; oc < MID; oc += 8) {
        float tv[8];
#pragma unroll
        for (int i = 0; i < 8; ++i) tv[i] = tl[oc + i][p];   // conflict-free
#pragma unroll
        for (int t = 0; t < NT; ++t)
#pragma unroll
            for (int i = 0; i < 8; ++i)
                aw[t] = fmaf(w2g[(T0 + t) * MID + oc + i], tv[i], aw[t]); // s_load
    }
#pragma unroll
    for (int t = 0; t < NT; ++t) wgt[T0 + t][p] = aw[t];
}

// Block = 512 threads = 128 pixels x 4 slots; grid (98,16) = 1568 blocks =
// 25088 waves (vs R6's 3136 -> occupancy was grid-capped at 19%).
// Slot q: Phase A computes taps [12q,12q+12) (q=3: 13); Phase B applies all
// 49 taps to channels [4q,4q+4). wgt lives only in LDS (never global).
__global__ __launch_bounds__(512) void k3_fused(const float* __restrict__ x,
                                                const float* __restrict__ w2,
                                                const float* __restrict__ b2,
                                                const float* __restrict__ ws,
                                                float* __restrict__ out) {
    __shared__ float tl[MID][128];                // 32 KB
    __shared__ float wgt[KK][128];                // 24.5 KB
    const int tid = threadIdx.x;
    const int p   = tid & 127;                    // local pixel
    const int q   = __builtin_amdgcn_readfirstlane(tid >> 7);  // slot, wave-uniform
    const int pix = blockIdx.x * 128 + p;         // 98 * 128 = 12544
    const int g   = blockIdx.y;                   // group (uniform)
    const int b   = pix / HWSZ;
    const int hw  = pix - b * HWSZ;
    const int h   = hw / WID;
    const int w   = hw - h * WID;

    // stage BN+ReLU(t): slot q stages rows o = [16q, 16q+16)
    {
        const float* tcol = ws + 256 + blockIdx.x * 128 + p;
#pragma unroll
        for (int i = 0; i < 16; ++i) {
            const int o = q * 16 + i;             // SGPR
            const float v = tcol[(size_t)o * NPIX];   // coalesced
            tl[o][p] = fmaxf(0.f, fmaf(ws[128 + o], v, ws[192 + o]));
        }
    }
    __syncthreads();

    const float* w2g = w2 + (size_t)g * KK * MID;
    const float* b2g = b2 + (size_t)g * KK;

    if      (q == 0) phaseA< 0, 12>(w2g, b2g, tl, wgt, p);
    else if (q == 1) phaseA<12, 12>(w2g, b2g, tl, wgt, p);
    else if (q == 2) phaseA<24, 12>(w2g, b2g, tl, wgt, p);
    else             phaseA<36, 13>(w2g, b2g, tl, wgt, p);
    __syncthreads();

    // Phase B: 4 channels per slot
    float acc[4] = {0.f, 0.f, 0.f, 0.f};
    const int xbase = (b * CIN + g * GCH + q * 4) * HWSZ;

#pragma unroll
    for (int t = 0; t < KK; ++t) {
        const int di = t / 7 - 3;
        const int dj = t % 7 - 3;
        const int hh = h + di;
        const int ww = w + dj;
        const bool ok = ((unsigned)hh < 56u) && ((unsigned)ww < 56u);
        const float wv = wgt[t][p];               // conflict-free
        const float wm = ok ? wv : 0.f;
        const int  off = ok ? (hh * WID + ww) : 0;
        const float* xb = x + xbase + off;
#pragma unroll
        for (int cc = 0; cc < 4; ++cc)
            acc[cc] = fmaf(wm, xb[(size_t)cc * HWSZ], acc[cc]);
    }

    float* ob = out + (size_t)xbase + hw;
#pragma unroll
    for (int cc = 0; cc < 4; ++cc) ob[(size_t)cc * HWSZ] = acc[cc];
}

extern "C" void kernel_launch(void* const* d_in, const int* in_sizes, int n_in,
                              void* d_out, int out_size, void* d_ws, size_t ws_size,
                              hipStream_t stream) {
    const float* x     = (const float*)d_in[0];
    const float* w1    = (const float*)d_in[1];
    const float* b1    = (const float*)d_in[2];
    const float* gamma = (const float*)d_in[3];
    const float* beta  = (const float*)d_in[4];
    const float* w2    = (const float*)d_in[5];
    const float* b2    = (const float*)d_in[6];
    float* out = (float*)d_out;
    float* ws  = (float*)d_ws;

    // zero the stats accumulators (first 128 floats)
    hipMemsetAsync(ws, 0, 128 * sizeof(float), stream);

    k1_conv1<<<dim3(49, 16), 256, 0, stream>>>(x, w1, b1, ws);
    k2_stats<<<1, 64, 0, stream>>>(ws, gamma, beta);
    k3_fused<<<dim3(98, 16), 512, 0, stream>>>(x, w2, b2, ws, out);
}